// Round 3
// baseline (102.224 us; speedup 1.0000x reference)
//
#include <hip/hip_runtime.h>
#include <math.h>

#define HW_PIX 65536   // 256*256
#define TDIM 512
#define NBATCH 16
#define BLK_PER_B 32           // 512 blocks total
#define PIX_PER_BLK 2048       // 256 thr * 8 px

typedef float v4f __attribute__((ext_vector_type(4)));

__device__ __forceinline__ float wred64(float v) {
#pragma unroll
    for (int off = 32; off > 0; off >>= 1) v += __shfl_xor(v, off, 64);
    return v;
}

// Single fused kernel. Every block independently recomputes:
//   t[b]   = text_proj_w @ text_vec[b] + text_proj_b       (64x512 dot, L2-hot)
//   u = Zw^T t, s = zb.t, tn = |t|^2                        (t-dependent, 5 scalars)
//   G = Zw^T Zw, M = out_w Zw, v = out_w zb, g = Zw^T zb, bn=|zb|^2  (weight-only)
// then streams 8 pixels/thread:  out = (1+sigmoid(k)) * (M q + v) + out_b
__global__ __launch_bounds__(256) void fused_all(
    const float* __restrict__ z,            // (16,3,256,256)
    const float* __restrict__ text_vec,     // (16,512)
    const float* __restrict__ z_proj_w,     // (64,3)
    const float* __restrict__ z_proj_b,     // (64)
    const float* __restrict__ text_proj_w,  // (64,512)
    const float* __restrict__ text_proj_b,  // (64)
    const float* __restrict__ out_w,        // (3,64)
    const float* __restrict__ out_bias,     // (3)
    const float* __restrict__ log_gamma,
    const float* __restrict__ alpha_p,
    const float* __restrict__ c_p,
    const float* __restrict__ wv,           // (3)
    float* __restrict__ out)                // (16,3,256,256)
{
    const int tid = threadIdx.x;
    const int b   = blockIdx.x >> 5;        // 32 blocks per batch
    const int pb  = blockIdx.x & 31;
    const int p0  = pb * PIX_PER_BLK + tid * 4;   // first float4; second at +1024

    // ---- issue the streaming loads NOW; they drain at the first barrier ----
    const float* zbase = z + (size_t)b * 3 * HW_PIX;
    v4f A0 = __builtin_nontemporal_load((const v4f*)(zbase + p0));
    v4f A1 = __builtin_nontemporal_load((const v4f*)(zbase + p0 + 1024));
    v4f B0 = __builtin_nontemporal_load((const v4f*)(zbase + HW_PIX + p0));
    v4f B1 = __builtin_nontemporal_load((const v4f*)(zbase + HW_PIX + p0 + 1024));
    v4f C0 = __builtin_nontemporal_load((const v4f*)(zbase + 2 * HW_PIX + p0));
    v4f C1 = __builtin_nontemporal_load((const v4f*)(zbase + 2 * HW_PIX + p0 + 1024));

    // scalar params (uniform, L1-broadcast)
    const float gamma = __expf(log_gamma[0]);
    const float alpha = alpha_p[0], cc = c_p[0];
    const float kw0 = wv[0], kw1 = wv[1], kw2 = wv[2];
    const float invw = 1.0f / (kw0 + kw1 + kw2 + 1e-8f);
    const float ob0 = out_bias[0], ob1 = out_bias[1], ob2 = out_bias[2];

    // ---- per-block prologue: t[b] via 4-lane-split 512-dots ----
    const int o = tid >> 2;                 // hidden channel 0..63
    const int q = tid & 3;                  // quarter of the 512-dot
    const float4* tv = (const float4*)(text_vec + (size_t)b * TDIM);
    const float4* wr = (const float4*)(text_proj_w + (size_t)o * TDIM);

    float acc = 0.f;
#pragma unroll 8
    for (int i = q * 32; i < q * 32 + 32; ++i) {
        float4 a = tv[i];
        float4 ww = wr[i];
        acc = fmaf(a.x, ww.x, fmaf(a.y, ww.y, fmaf(a.z, ww.z, fmaf(a.w, ww.w, acc))));
    }
    acc += __shfl_xor(acc, 1, 64);
    acc += __shfl_xor(acc, 2, 64);

    __shared__ float t_sh[64];
    __shared__ float c_sh[32];
    if (q == 0) t_sh[o] = acc + text_proj_b[o];
    __syncthreads();

    if (tid < 64) {     // wave 0 computes all 27 reduction constants
        const float t  = t_sh[tid];
        const float w0 = z_proj_w[tid * 3 + 0];
        const float w1 = z_proj_w[tid * 3 + 1];
        const float w2 = z_proj_w[tid * 3 + 2];
        const float zb = z_proj_b[tid];
        const float o0 = out_w[0 * 64 + tid];
        const float o1 = out_w[1 * 64 + tid];
        const float o2 = out_w[2 * 64 + tid];

        float u0 = wred64(w0 * t),  u1 = wred64(w1 * t),  u2 = wred64(w2 * t);
        float s  = wred64(zb * t),  tn = wred64(t * t);
        float G00 = wred64(w0 * w0), G01 = wred64(w0 * w1), G02 = wred64(w0 * w2);
        float G11 = wred64(w1 * w1), G12 = wred64(w1 * w2), G22 = wred64(w2 * w2);
        float M00 = wred64(o0 * w0), M01 = wred64(o0 * w1), M02 = wred64(o0 * w2);
        float M10 = wred64(o1 * w0), M11 = wred64(o1 * w1), M12 = wred64(o1 * w2);
        float M20 = wred64(o2 * w0), M21 = wred64(o2 * w1), M22 = wred64(o2 * w2);
        float v0  = wred64(o0 * zb), v1  = wred64(o1 * zb), v2  = wred64(o2 * zb);
        float g0  = wred64(w0 * zb), g1  = wred64(w1 * zb), g2  = wred64(w2 * zb);
        float bn  = wred64(zb * zb);
        if (tid == 0) {
            c_sh[0] = u0;  c_sh[1] = u1;  c_sh[2] = u2;  c_sh[3] = s;   c_sh[4] = tn;
            c_sh[5] = G00; c_sh[6] = G01; c_sh[7] = G02; c_sh[8] = G11; c_sh[9] = G12; c_sh[10] = G22;
            c_sh[11] = M00; c_sh[12] = M01; c_sh[13] = M02;
            c_sh[14] = M10; c_sh[15] = M11; c_sh[16] = M12;
            c_sh[17] = M20; c_sh[18] = M21; c_sh[19] = M22;
            c_sh[20] = v0;  c_sh[21] = v1;  c_sh[22] = v2;
            c_sh[23] = g0;  c_sh[24] = g1;  c_sh[25] = g2;
            c_sh[26] = bn;
        }
    }
    __syncthreads();

    const float u0 = c_sh[0], u1 = c_sh[1], u2 = c_sh[2], s = c_sh[3], tn = c_sh[4];
    const float G00 = c_sh[5], G01 = c_sh[6], G02 = c_sh[7], G11 = c_sh[8], G12 = c_sh[9], G22 = c_sh[10];
    const float M00 = c_sh[11], M01 = c_sh[12], M02 = c_sh[13];
    const float M10 = c_sh[14], M11 = c_sh[15], M12 = c_sh[16];
    const float M20 = c_sh[17], M21 = c_sh[18], M22 = c_sh[19];
    const float v0 = c_sh[20], v1 = c_sh[21], v2 = c_sh[22];
    const float g0 = c_sh[23], g1 = c_sh[24], g2 = c_sh[25], bn = c_sh[26];

    const float e0 = g0 - u0, e1 = g1 - u1, e2 = g2 - u2;
    const float d0 = bn - 2.f * s + tn;

    float X[8] = {A0.x, A0.y, A0.z, A0.w, A1.x, A1.y, A1.z, A1.w};
    float Y[8] = {B0.x, B0.y, B0.z, B0.w, B1.x, B1.y, B1.z, B1.w};
    float Z[8] = {C0.x, C0.y, C0.z, C0.w, C1.x, C1.y, C1.z, C1.w};
    float O0[8], O1[8], O2[8];

#pragma unroll
    for (int j = 0; j < 8; ++j) {
        const float x = X[j], y = Y[j], zc = Z[j];
        const float klin = fmaf(x, u0, fmaf(y, u1, fmaf(zc, u2, s)));
        const float quad = x * fmaf(2.f, fmaf(G01, y, G02 * zc), G00 * x)
                         + y * fmaf(2.f, G12 * zc, G11 * y)
                         + G22 * zc * zc;
        const float dist = quad + 2.f * fmaf(e0, x, fmaf(e1, y, e2 * zc)) + d0;
        const float krbf = __expf(-gamma * dist);
        float kp = fmaf(alpha, klin, cc);
        kp = kp * kp;
        const float k = (kw0 * krbf + kw1 * klin + kw2 * kp) * invw;
        const float sig = 1.f / (1.f + __expf(-k));
        const float scale = 1.f + sig;

        const float m0 = fmaf(M00, x, fmaf(M01, y, fmaf(M02, zc, v0)));
        const float m1 = fmaf(M10, x, fmaf(M11, y, fmaf(M12, zc, v1)));
        const float m2 = fmaf(M20, x, fmaf(M21, y, fmaf(M22, zc, v2)));
        O0[j] = fmaf(scale, m0, ob0);
        O1[j] = fmaf(scale, m1, ob1);
        O2[j] = fmaf(scale, m2, ob2);
    }

    float* obase = out + (size_t)b * 3 * HW_PIX;
    v4f R;
    R.x = O0[0]; R.y = O0[1]; R.z = O0[2]; R.w = O0[3];
    __builtin_nontemporal_store(R, (v4f*)(obase + p0));
    R.x = O0[4]; R.y = O0[5]; R.z = O0[6]; R.w = O0[7];
    __builtin_nontemporal_store(R, (v4f*)(obase + p0 + 1024));
    R.x = O1[0]; R.y = O1[1]; R.z = O1[2]; R.w = O1[3];
    __builtin_nontemporal_store(R, (v4f*)(obase + HW_PIX + p0));
    R.x = O1[4]; R.y = O1[5]; R.z = O1[6]; R.w = O1[7];
    __builtin_nontemporal_store(R, (v4f*)(obase + HW_PIX + p0 + 1024));
    R.x = O2[0]; R.y = O2[1]; R.z = O2[2]; R.w = O2[3];
    __builtin_nontemporal_store(R, (v4f*)(obase + 2 * HW_PIX + p0));
    R.x = O2[4]; R.y = O2[5]; R.z = O2[6]; R.w = O2[7];
    __builtin_nontemporal_store(R, (v4f*)(obase + 2 * HW_PIX + p0 + 1024));
}

extern "C" void kernel_launch(void* const* d_in, const int* in_sizes, int n_in,
                              void* d_out, int out_size, void* d_ws, size_t ws_size,
                              hipStream_t stream) {
    const float* z           = (const float*)d_in[0];
    const float* text_vec    = (const float*)d_in[1];
    const float* z_proj_w    = (const float*)d_in[2];
    const float* z_proj_b    = (const float*)d_in[3];
    const float* text_proj_w = (const float*)d_in[4];
    const float* text_proj_b = (const float*)d_in[5];
    const float* out_w       = (const float*)d_in[6];
    const float* out_b       = (const float*)d_in[7];
    const float* log_gamma   = (const float*)d_in[8];
    const float* alpha       = (const float*)d_in[9];
    const float* c           = (const float*)d_in[10];
    const float* w           = (const float*)d_in[11];
    float* out = (float*)d_out;

    fused_all<<<NBATCH * BLK_PER_B, 256, 0, stream>>>(
        z, text_vec, z_proj_w, z_proj_b, text_proj_w, text_proj_b,
        out_w, out_b, log_gamma, alpha, c, w, out);
}

// Round 4
// 97.756 us; speedup vs baseline: 1.0457x; 1.0457x over previous
//
#include <hip/hip_runtime.h>
#include <math.h>

#define HW_PIX 65536   // 256*256
#define TDIM 512
#define NBATCH 16

typedef float v4f __attribute__((ext_vector_type(4)));

__device__ __forceinline__ float wred64(float v) {
#pragma unroll
    for (int off = 32; off > 0; off >>= 1) v += __shfl_xor(v, off, 64);
    return v;
}

// ws layout (floats):
//  [b*8 + 0..4]  : u0,u1,u2, s, tnorm           (per batch b = 0..15)
//  [128 + 0..5]  : G00,G01,G02,G11,G12,G22
//  [128 + 6..14] : M row-major (3x3)
//  [128 +15..17] : v
//  [128 +18..20] : g
//  [128 +21]     : bnorm
//  [128 +22..24] : kw0*invw, kw1*invw, kw2*invw (pre-scaled kernel weights)
__global__ __launch_bounds__(256) void prep_kernel(
    const float* __restrict__ text_vec,    // (16,512)
    const float* __restrict__ text_proj_w, // (64,512)
    const float* __restrict__ text_proj_b, // (64)
    const float* __restrict__ z_proj_w,    // (64,3)
    const float* __restrict__ z_proj_b,    // (64)
    const float* __restrict__ out_w,       // (3,64)
    const float* __restrict__ wv,          // (3)
    float* __restrict__ ws)
{
    const int b   = blockIdx.x;
    const int tid = threadIdx.x;
    const int o   = tid >> 2;   // output channel 0..63
    const int q   = tid & 3;    // quarter of the 512-dot

    const float4* tv   = (const float4*)(text_vec + (size_t)b * TDIM);
    const float4* wrow = (const float4*)(text_proj_w + (size_t)o * TDIM);

    float acc = 0.f;
#pragma unroll 8
    for (int i = q * 32; i < q * 32 + 32; ++i) {
        float4 a = tv[i];
        float4 w = wrow[i];
        acc = fmaf(a.x, w.x, fmaf(a.y, w.y, fmaf(a.z, w.z, fmaf(a.w, w.w, acc))));
    }
    acc += __shfl_xor(acc, 1, 64);
    acc += __shfl_xor(acc, 2, 64);

    __shared__ float t_sh[64];
    if (q == 0) t_sh[o] = acc + text_proj_b[o];
    __syncthreads();

    if (tid < 64) {   // wave 0 does all reductions
        float t  = t_sh[tid];
        float w0 = z_proj_w[tid * 3 + 0];
        float w1 = z_proj_w[tid * 3 + 1];
        float w2 = z_proj_w[tid * 3 + 2];
        float zb = z_proj_b[tid];

        float u0 = wred64(w0 * t);
        float u1 = wred64(w1 * t);
        float u2 = wred64(w2 * t);
        float s  = wred64(zb * t);
        float tn = wred64(t * t);
        if (tid == 0) {
            float* pb = ws + b * 8;
            pb[0] = u0; pb[1] = u1; pb[2] = u2; pb[3] = s; pb[4] = tn;
        }

        if (b == 0) {   // weight-only constants, computed once
            float o0 = out_w[0 * 64 + tid];
            float o1 = out_w[1 * 64 + tid];
            float o2 = out_w[2 * 64 + tid];
            float G00 = wred64(w0 * w0), G01 = wred64(w0 * w1), G02 = wred64(w0 * w2);
            float G11 = wred64(w1 * w1), G12 = wred64(w1 * w2), G22 = wred64(w2 * w2);
            float M00 = wred64(o0 * w0), M01 = wred64(o0 * w1), M02 = wred64(o0 * w2);
            float M10 = wred64(o1 * w0), M11 = wred64(o1 * w1), M12 = wred64(o1 * w2);
            float M20 = wred64(o2 * w0), M21 = wred64(o2 * w1), M22 = wred64(o2 * w2);
            float v0  = wred64(o0 * zb), v1  = wred64(o1 * zb), v2  = wred64(o2 * zb);
            float g0  = wred64(w0 * zb), g1  = wred64(w1 * zb), g2  = wred64(w2 * zb);
            float bn  = wred64(zb * zb);
            if (tid == 0) {
                float* c = ws + 128;
                c[0] = G00; c[1] = G01; c[2] = G02; c[3] = G11; c[4] = G12; c[5] = G22;
                c[6] = M00; c[7] = M01; c[8] = M02;
                c[9] = M10; c[10] = M11; c[11] = M12;
                c[12] = M20; c[13] = M21; c[14] = M22;
                c[15] = v0; c[16] = v1; c[17] = v2;
                c[18] = g0; c[19] = g1; c[20] = g2;
                c[21] = bn;
                const float kw0 = wv[0], kw1 = wv[1], kw2 = wv[2];
                const float invw = 1.0f / (kw0 + kw1 + kw2 + 1e-8f);
                c[22] = kw0 * invw; c[23] = kw1 * invw; c[24] = kw2 * invw;
            }
        }
    }
}

__global__ __launch_bounds__(256) void fuse_kernel(
    const float* __restrict__ z,        // (16,3,256,256)
    const float* __restrict__ out_bias, // (3)
    const float* __restrict__ log_gamma,
    const float* __restrict__ alpha_p,
    const float* __restrict__ c_p,
    const float* __restrict__ ws,
    float* __restrict__ out)            // (16,3,256,256)
{
    const int blk = blockIdx.x;
    const int b   = blk >> 6;                                   // 64 blocks per batch
    const int p   = ((blk & 63) << 10) + (threadIdx.x << 2);    // pixel offset (4/thread)

    // streaming loads first — overlap with the (uniform, scalar) constant loads
    const float* zb = z + (size_t)b * 3 * HW_PIX + p;
    v4f q0 = __builtin_nontemporal_load((const v4f*)(zb));
    v4f q1 = __builtin_nontemporal_load((const v4f*)(zb + HW_PIX));
    v4f q2 = __builtin_nontemporal_load((const v4f*)(zb + 2 * HW_PIX));

    const float* C = ws + 128;
    const float G00 = C[0], G01 = C[1], G02 = C[2], G11 = C[3], G12 = C[4], G22 = C[5];
    const float M00 = C[6], M01 = C[7], M02 = C[8];
    const float M10 = C[9], M11 = C[10], M12 = C[11];
    const float M20 = C[12], M21 = C[13], M22 = C[14];
    const float v0 = C[15], v1 = C[16], v2 = C[17];
    const float g0 = C[18], g1 = C[19], g2 = C[20], bn = C[21];
    const float kw0 = C[22], kw1 = C[23], kw2 = C[24];  // pre-scaled by invw

    const float* pb = ws + b * 8;
    const float u0 = pb[0], u1 = pb[1], u2 = pb[2], s = pb[3], tn = pb[4];

    const float gamma = __expf(log_gamma[0]);
    const float alpha = alpha_p[0], cc = c_p[0];
    const float ob0 = out_bias[0], ob1 = out_bias[1], ob2 = out_bias[2];

    const float e0 = g0 - u0, e1 = g1 - u1, e2 = g2 - u2;
    const float d0 = bn - 2.f * s + tn;

    float X[4] = {q0.x, q0.y, q0.z, q0.w};
    float Y[4] = {q1.x, q1.y, q1.z, q1.w};
    float Z[4] = {q2.x, q2.y, q2.z, q2.w};
    float O0[4], O1[4], O2[4];

#pragma unroll
    for (int j = 0; j < 4; ++j) {
        const float x = X[j], y = Y[j], zc = Z[j];
        const float klin = fmaf(x, u0, fmaf(y, u1, fmaf(zc, u2, s)));
        const float quad = x * fmaf(2.f, fmaf(G01, y, G02 * zc), G00 * x)
                         + y * fmaf(2.f, G12 * zc, G11 * y)
                         + G22 * zc * zc;
        const float dist = quad + 2.f * fmaf(e0, x, fmaf(e1, y, e2 * zc)) + d0;
        const float krbf = __expf(-gamma * dist);
        float kp = fmaf(alpha, klin, cc);
        kp = kp * kp;
        const float k = fmaf(kw0, krbf, fmaf(kw1, klin, kw2 * kp));
        const float sig = 1.f / (1.f + __expf(-k));
        const float scale = 1.f + sig;

        const float m0 = fmaf(M00, x, fmaf(M01, y, fmaf(M02, zc, v0)));
        const float m1 = fmaf(M10, x, fmaf(M11, y, fmaf(M12, zc, v1)));
        const float m2 = fmaf(M20, x, fmaf(M21, y, fmaf(M22, zc, v2)));
        O0[j] = fmaf(scale, m0, ob0);
        O1[j] = fmaf(scale, m1, ob1);
        O2[j] = fmaf(scale, m2, ob2);
    }

    float* ob = out + (size_t)b * 3 * HW_PIX + p;
    v4f R;
    R.x = O0[0]; R.y = O0[1]; R.z = O0[2]; R.w = O0[3];
    __builtin_nontemporal_store(R, (v4f*)(ob));
    R.x = O1[0]; R.y = O1[1]; R.z = O1[2]; R.w = O1[3];
    __builtin_nontemporal_store(R, (v4f*)(ob + HW_PIX));
    R.x = O2[0]; R.y = O2[1]; R.z = O2[2]; R.w = O2[3];
    __builtin_nontemporal_store(R, (v4f*)(ob + 2 * HW_PIX));
}

extern "C" void kernel_launch(void* const* d_in, const int* in_sizes, int n_in,
                              void* d_out, int out_size, void* d_ws, size_t ws_size,
                              hipStream_t stream) {
    const float* z           = (const float*)d_in[0];
    const float* text_vec    = (const float*)d_in[1];
    const float* z_proj_w    = (const float*)d_in[2];
    const float* z_proj_b    = (const float*)d_in[3];
    const float* text_proj_w = (const float*)d_in[4];
    const float* text_proj_b = (const float*)d_in[5];
    const float* out_w       = (const float*)d_in[6];
    const float* out_b       = (const float*)d_in[7];
    const float* log_gamma   = (const float*)d_in[8];
    const float* alpha       = (const float*)d_in[9];
    const float* c           = (const float*)d_in[10];
    const float* w           = (const float*)d_in[11];
    float* out = (float*)d_out;
    float* ws  = (float*)d_ws;

    prep_kernel<<<NBATCH, 256, 0, stream>>>(text_vec, text_proj_w, text_proj_b,
                                            z_proj_w, z_proj_b, out_w, w, ws);
    fuse_kernel<<<NBATCH * 64, 256, 0, stream>>>(z, out_b, log_gamma, alpha, c,
                                                 ws, out);
}